// Round 10
// baseline (32.163 us; speedup 1.0000x reference)
//
#include <hip/hip_runtime.h>

// RankingBCELoss: loss = (1/(n_pos*n_neg)) * sum_{p,n} log(1 + e^{x_n} * e^{-x_p})
// R10: ONE kernel node, no memsets, no separate finalize.
//   - 512 blocks x 512 thr; block owns 32 raw rows; wave 0 ballot-compacts the
//     k positives' e^{-x} into LDS (one barrier), k rounded to 8 -> template
//     row_stream<NQ=1..4> (static indices only; rule #20 safe).
//   - columns streamed masked from global (en = t==0 ? e^x : 0, L2-resident,
//     unroll 4 for load pipelining); masked terms fma(0,emp,1)=1 absorbed free
//     by the product-of-8 trick (1 v_log_f32 per 8 rows per column).
//   - finalize folded in via TWO-LEVEL arrival (fan-in 16 -> 32): worst-case
//     serialized-RMW tail ~1.2us (R3-vs-R7 lesson: same-address RMW ~25ns,
//     cost = queue depth at simultaneous retirement; keep fan-in small).
//   - MODULO-EPOCH counters: "last" = ((old+1) % target == 0). Each counter
//     gets exactly `target` increments per launch, so this fires exactly once
//     per launch from ANY initial value -> poison-proof, no reset node needed,
//     self-consistent across graph replays. Winner does fixed-order reduce ->
//     deterministic output regardless of which block wins.

#define PT   512           // threads per block (8 waves)
#define RB   32            // raw rows per block
#define NL1  32            // level-1 arrival counters (fan-in nblocks/NL1 = 16)

template<int NQ>
__device__ __forceinline__ float row_stream(const float* __restrict__ lds_emp,
                                            const float4* __restrict__ x4,
                                            const int4* __restrict__ t4,
                                            int n4, int tid) {
    float emp[NQ * 8];                       // template-static indices => registers
#pragma unroll
    for (int r = 0; r < NQ * 8; ++r) emp[r] = lds_emp[r];
    float acc[NQ];
#pragma unroll
    for (int q = 0; q < NQ; ++q) acc[q] = 0.f;

    auto do_col = [&](float xc, int tc) {
        const float en = (tc == 0) ? __expf(xc) : 0.f;   // masked negative
        // terms in [1, ~1e4]; product of 8 <= ~1e32 < 3.4e38: safe
#pragma unroll
        for (int q = 0; q < NQ; ++q) {
            float p0 = __builtin_fmaf(en, emp[q * 8 + 0], 1.f);
            p0 *= __builtin_fmaf(en, emp[q * 8 + 1], 1.f);
            p0 *= __builtin_fmaf(en, emp[q * 8 + 2], 1.f);
            p0 *= __builtin_fmaf(en, emp[q * 8 + 3], 1.f);
            float p1 = __builtin_fmaf(en, emp[q * 8 + 4], 1.f);
            p1 *= __builtin_fmaf(en, emp[q * 8 + 5], 1.f);
            p1 *= __builtin_fmaf(en, emp[q * 8 + 6], 1.f);
            p1 *= __builtin_fmaf(en, emp[q * 8 + 7], 1.f);
            acc[q] += __log2f(p0 * p1);      // 1 log per 8 (real or masked) rows
        }
    };

#pragma unroll 4
    for (int v = tid; v < n4; v += PT) {     // coalesced float4/int4; L2-resident
        const float4 xv = x4[v];
        const int4   tv = t4[v];
        do_col(xv.x, tv.x);
        do_col(xv.y, tv.y);
        do_col(xv.z, tv.z);
        do_col(xv.w, tv.w);
    }
    float s = 0.f;
#pragma unroll
    for (int q = 0; q < NQ; ++q) s += acc[q];
    return s;
}

__global__ __launch_bounds__(PT)
void ranking_bce_one(const float* __restrict__ x, const int* __restrict__ tg, int n,
                     double* __restrict__ partials, unsigned* __restrict__ c1,
                     unsigned* __restrict__ c2, float* __restrict__ out) {
    __shared__ float  lds_emp[RB];
    __shared__ int    lds_k;
    __shared__ double wsum[PT / 64];
    __shared__ double fs[PT / 64];
    __shared__ int    fc[PT / 64];
    __shared__ int    lastFlag;
    const int bid = blockIdx.x, tid = threadIdx.x;
    const int lane = tid & 63, wid = tid >> 6;
    const int nblocks = (int)gridDim.x;
    const int rbase = bid * RB;

    // ---- wave 0: ballot-compact this block's positive rows into LDS ----
    if (wid == 0) {
        float ex = 0.f; int isp = 0;
        if (lane < RB) {
            const int t = tg[rbase + lane];
            isp = (t == 1);
            if (isp) ex = __expf(-x[rbase + lane]);
        }
        const unsigned long long m = __ballot(isp);
        if (lane < RB) lds_emp[lane] = 0.f;  // same-wave order: rank store below wins
        const int rank = (int)__popcll(m & ((1ull << lane) - 1ull));
        if (isp) lds_emp[rank] = ex;
        if (lane == 0) lds_k = (int)__popcll(m);
    }
    __syncthreads();                         // only barrier before reductions

    const int kq = (lds_k + 7) >> 3;         // 0..4 groups of 8 rows
    float s = 0.f;
    if (kq > 0) {
        const float4* x4 = (const float4*)x;
        const int4*   t4 = (const int4*)tg;
        const int n4 = n >> 2;
        switch (kq) {                        // template dispatch: static indexing only
            case 1:  s = row_stream<1>(lds_emp, x4, t4, n4, tid); break;
            case 2:  s = row_stream<2>(lds_emp, x4, t4, n4, tid); break;
            case 3:  s = row_stream<3>(lds_emp, x4, t4, n4, tid); break;
            default: s = row_stream<4>(lds_emp, x4, t4, n4, tid); break;
        }
    }

    // ---- block reduction -> partials[bid] ----
#pragma unroll
    for (int off = 32; off > 0; off >>= 1) s += __shfl_down(s, off, 64);
    if (lane == 0) wsum[wid] = (double)s;
    __syncthreads();
    if (tid == 0) {
        double b = 0.0;
#pragma unroll
        for (int w = 0; w < PT / 64; ++w) b += wsum[w];
        partials[bid] = b;
        __threadfence();                     // publish partial before arrival
        int lf = 0;
        const int g = bid & (NL1 - 1);
        const unsigned t1 = (unsigned)((nblocks - g + NL1 - 1) / NL1);  // 16
        const unsigned o1 = __hip_atomic_fetch_add(&c1[g], 1u, __ATOMIC_ACQ_REL,
                                                   __HIP_MEMORY_SCOPE_AGENT);
        if ((o1 + 1u) % t1 == 0u) {          // group winner (exactly 1/launch/group)
            const unsigned o2 = __hip_atomic_fetch_add(c2, 1u, __ATOMIC_ACQ_REL,
                                                       __HIP_MEMORY_SCOPE_AGENT);
            if ((o2 + 1u) % (unsigned)NL1 == 0u) lf = 1;   // global winner
        }
        lastFlag = lf;
    }
    __syncthreads();

    // ---- last-arriving block finalizes (fixed-order reduce: deterministic) ----
    if (lastFlag) {
        __threadfence();                     // acquire side belt-and-suspenders
        int cp = 0, cn = 0;
        const int4* t4 = (const int4*)tg;
        for (int v = tid; v < (n >> 2); v += PT) {
            const int4 t = t4[v];
            cp += (t.x == 1) + (t.y == 1) + (t.z == 1) + (t.w == 1);
            cn += (t.x == 0) + (t.y == 0) + (t.z == 0) + (t.w == 0);
        }
        double d = 0.0;
        for (int k = tid; k < nblocks; k += PT) d += partials[k];
        int c = cp | (cn << 16);
#pragma unroll
        for (int off = 32; off > 0; off >>= 1) {
            d += __shfl_down(d, off, 64);
            c += __shfl_down(c, off, 64);
        }
        if (lane == 0) { fs[wid] = d; fc[wid] = c; }
        __syncthreads();
        if (tid == 0) {
            double ssum = 0.0; int tot = 0;
#pragma unroll
            for (int w = 0; w < PT / 64; ++w) { ssum += fs[w]; tot += fc[w]; }
            const int np = tot & 0xffff, nn = tot >> 16;
            const double npairs = (double)np * (double)nn;
            out[0] = (npairs > 0.0) ? (float)(ssum * 0.6931471805599453 / npairs) : 0.0f;
        }
    }
}

extern "C" void kernel_launch(void* const* d_in, const int* in_sizes, int n_in,
                              void* d_out, int out_size, void* d_ws, size_t ws_size,
                              hipStream_t stream) {
    const float* x  = (const float*)d_in[0];
    const int*   tg = (const int*)d_in[1];
    const int n = in_sizes[0];                 // 16384

    char* ws = (char*)d_ws;
    double*   partials = (double*)(ws);        // 512 doubles = 4 KB
    unsigned* c1       = (unsigned*)(ws + 8192);        // 32 counters
    unsigned* c2       = (unsigned*)(ws + 8192 + 128);  // 1 counter
    // No reset needed: modulo-epoch arrivals are correct from any initial value.

    const int nblocks = (n + RB - 1) / RB;     // 512
    ranking_bce_one<<<nblocks, PT, 0, stream>>>(x, tg, n, partials, c1, c2,
                                                (float*)d_out);
}

// Round 11
// 20.253 us; speedup vs baseline: 1.5881x; 1.5881x over previous
//
#include <hip/hip_runtime.h>

// RankingBCELoss: loss = (1/(n_pos*n_neg)) * sum_{p,n} log(1 + e^{x_n} * e^{-x_p})
// R11: parallel deterministic compaction + verified cheap pair/finalize kernels.
//   K1 pcompact (64 blocks x 256 thr): block b counts tg[0..b*256) directly
//     (L2-resident, no cross-block comm) for its global write base, then
//     ballot-scan compacts its 256-element segment: pos_emp[i]=e^{-x_pos},
//     neg_en[j]=e^{x_neg} (last block zero-pads to x4 and writes cnts).
//     No atomics, no fences -> no serialized tails (R4/R7/R10 lesson).
//   K2 pair (R8 verbatim, verified): 1024 blocks x 512 thr, RB=16 compacted
//     rows in VGPRs (static indices), streams compacted neg_en float4s from
//     global (L2-resident, zero intra-block reuse -> no LDS). Per col:
//     16 fma + 14 mul + 2 v_log_f32 (product-of-8 trick). Wave partials ->
//     disjoint wpart slots.
//   K3 finalize (R8 verbatim): one block reduces wpart + cnts -> out.

#define K1B  64            // compact blocks
#define K1T  256           // compact threads (= segment size)
#define PT2  512           // pair kernel threads (8 waves)
#define RB   16            // rows per pair block
#define NW   (PT2 / 64)    // waves per pair block

// ---- Kernel 1: parallel compaction + exp precompute -----------------------
__global__ __launch_bounds__(K1T)
void pcompact(const float* __restrict__ x, const int* __restrict__ tg, int n,
              float* __restrict__ pos_emp, float* __restrict__ neg_en,
              int* __restrict__ cnts) {
    __shared__ int wred[K1T / 64], wvc[K1T / 64], base_s, tots;
    const int b = blockIdx.x, t = threadIdx.x;
    const int lane = t & 63, w = t >> 6;
    const int s0 = b * K1T;                  // segment start (n = K1B*K1T)

    // phase 1: prefix counts over [0, s0) — packed (pos | neg<<16)
    int cp = 0, cn = 0;
    const int4* t4 = (const int4*)tg;
    for (int v = t; v < (s0 >> 2); v += K1T) {
        const int4 tv = t4[v];
        cp += (tv.x == 1) + (tv.y == 1) + (tv.z == 1) + (tv.w == 1);
        cn += (tv.x == 0) + (tv.y == 0) + (tv.z == 0) + (tv.w == 0);
    }
    int pk = cp | (cn << 16);                // fields <= 16384: no carry
#pragma unroll
    for (int off = 32; off > 0; off >>= 1) pk += __shfl_down(pk, off, 64);
    if (lane == 0) wred[w] = pk;
    __syncthreads();
    if (t == 0) {
        int s = 0;
#pragma unroll
        for (int i = 0; i < K1T / 64; ++i) s += wred[i];
        base_s = s;                          // packed {pbase, nbase<<16}
    }

    // phase 2: ballot-compact this segment (1 element per thread)
    const int e = s0 + t;
    const int   tv = (e < n) ? tg[e] : -1;
    const float xv = (e < n) ? x[e] : 0.f;
    const int isp = (tv == 1), isn = (tv == 0);
    const unsigned long long mp = __ballot(isp);
    const unsigned long long mn = __ballot(isn);
    if (lane == 0) wvc[w] = (int)__popcll(mp) | ((int)__popcll(mn) << 16);
    __syncthreads();                         // publishes base_s and wvc[]
    int pre = 0;
    for (int i = 0; i < w; ++i) pre += wvc[i];   // wave-exclusive prefix (packed)
    const unsigned long long ltm = (1ull << lane) - 1ull;
    if (isp) {
        const int idx = (base_s & 0xffff) + (pre & 0xffff) + (int)__popcll(mp & ltm);
        pos_emp[idx] = __expf(-xv);          // e^{-x_pos}
    } else if (isn) {
        const int idx = ((base_s >> 16) & 0xffff) + ((pre >> 16) & 0xffff)
                        + (int)__popcll(mn & ltm);
        neg_en[idx] = __expf(xv);            // e^{x_neg}
    }

    // last block: totals, zero-pad neg_en to x4, write cnts
    if (b == K1B - 1) {
        __syncthreads();                     // block-uniform condition: legal
        if (t == 0) {
            int s = base_s;
#pragma unroll
            for (int i = 0; i < K1T / 64; ++i) s += wvc[i];
            tots = s;
        }
        __syncthreads();
        const int np = tots & 0xffff, nn = (tots >> 16) & 0xffff;
        const int nn_pad = (nn + 3) & ~3;
        for (int i = nn + t; i < nn_pad; i += K1T) neg_en[i] = 0.f;  // pad -> term=1
        if (t == 0) { cnts[0] = np; cnts[1] = nn; cnts[2] = nn_pad; }
    }
}

// ---- Kernel 2: register-tiled pairs; barrier-free, LDS-free, atomic-free ---
__global__ __launch_bounds__(PT2)
void pair_kernel(const float* __restrict__ pos_emp, const float* __restrict__ neg_en,
                 const int* __restrict__ cnts, double* __restrict__ wpart) {
    const int bid = blockIdx.x, tid = threadIdx.x;
    const int wid = tid >> 6, lane = tid & 63;
    const int gw  = bid * NW + wid;          // global wave index (disjoint slot)
    const int np = cnts[0];
    const int nnpad4 = cnts[2] >> 2;
    const int rbase = bid * RB;

    if (rbase >= np || nnpad4 == 0) {        // block-uniform early out
        if (lane == 0) wpart[gw] = 0.0;
        return;
    }

    float emp[RB];                           // static-indexed only => registers
#pragma unroll
    for (int r = 0; r < RB; ++r) {
        const int row = rbase + r;           // block-uniform address
        emp[r] = (row < np) ? pos_emp[row] : 0.f;   // OOR row contributes 0
    }

    float acc0 = 0.f, acc1 = 0.f;
#define TERM(EN, R)  __builtin_fmaf((EN), emp[R], 1.0f)
#define Q4(EN, R0)   (((TERM(EN,R0) * TERM(EN,(R0)+1)) * TERM(EN,(R0)+2)) * TERM(EN,(R0)+3))
    // terms in [1, ~2e4]; product of 8 <= ~6e34 < 3.4e38: safe
#define DO_COL(EN)                                      \
    do {                                                \
        const float en_ = (EN);                         \
        acc0 += __log2f(Q4(en_, 0) * Q4(en_, 4));       \
        acc1 += __log2f(Q4(en_, 8) * Q4(en_, 12));      \
    } while (0)

    const float4* __restrict__ en4 = (const float4*)neg_en;
#pragma unroll 2
    for (int v4 = tid; v4 < nnpad4; v4 += PT2) {   // coalesced; L2-resident
        const float4 e4 = en4[v4];
        DO_COL(e4.x);
        DO_COL(e4.y);
        DO_COL(e4.z);
        DO_COL(e4.w);
    }
#undef DO_COL
#undef Q4
#undef TERM

    float s = acc0 + acc1;
#pragma unroll
    for (int off = 32; off > 0; off >>= 1) s += __shfl_down(s, off, 64);
    if (lane == 0) wpart[gw] = (double)s;    // disjoint f64 write; no contention
}

// ---- Kernel 3: reduce wave partials + finalize ----------------------------
__global__ __launch_bounds__(1024)
void finalize_kernel(const int* __restrict__ cnts, const double* __restrict__ wpart,
                     int nwaves, float* __restrict__ out) {
    const int tid = threadIdx.x;
    double d = 0.0;
    for (int k = tid; k < nwaves; k += 1024) d += wpart[k];   // fixed order
#pragma unroll
    for (int off = 32; off > 0; off >>= 1) d += __shfl_down(d, off, 64);
    __shared__ double fsum[16];
    if ((tid & 63) == 0) fsum[tid >> 6] = d;
    __syncthreads();
    if (tid == 0) {
        double s = 0.0;
#pragma unroll
        for (int w = 0; w < 16; ++w) s += fsum[w];
        const double npairs = (double)cnts[0] * (double)cnts[1];
        out[0] = (npairs > 0.0) ? (float)(s * 0.6931471805599453 / npairs) : 0.0f;
    }
}

extern "C" void kernel_launch(void* const* d_in, const int* in_sizes, int n_in,
                              void* d_out, int out_size, void* d_ws, size_t ws_size,
                              hipStream_t stream) {
    const float* x  = (const float*)d_in[0];
    const int*   tg = (const int*)d_in[1];
    const int n = in_sizes[0];                 // 16384 (= K1B * K1T)

    char* ws = (char*)d_ws;
    float*  pos_emp = (float*)(ws);            // 64 KB
    float*  neg_en  = (float*)(ws + 65536);    // 64 KB + pad
    int*    cnts    = (int*)(ws + 135168);     // 3 ints
    double* wpart   = (double*)(ws + 139264);  // 8192 doubles = 64 KB

    const int nblocks = (n + RB - 1) / RB;     // 1024 (worst case: all positive)
    const int nwaves  = nblocks * NW;          // 8192
    pcompact<<<K1B, K1T, 0, stream>>>(x, tg, n, pos_emp, neg_en, cnts);
    pair_kernel<<<nblocks, PT2, 0, stream>>>(pos_emp, neg_en, cnts, wpart);
    finalize_kernel<<<1, 1024, 0, stream>>>(cnts, wpart, nwaves, (float*)d_out);
}